// Round 11
// baseline (1953.250 us; speedup 1.0000x reference)
//
#include <hip/hip_runtime.h>
#include <cmath>

namespace {
constexpr int B_ = 16, T_ = 512, P_ = 256, E_ = 128, NB_ = 4, K_ = 4;
constexpr int THREADS_ = 512;
constexpr int RS_ = 132;   // padded ring row stride (floats): rows shift banks by 4

typedef float v2f __attribute__((ext_vector_type(2)));
typedef int   v2i __attribute__((ext_vector_type(2)));
__device__ __forceinline__ v2f v2s(float s) { return (v2f){s, s}; }
__device__ __forceinline__ v2f vfma(v2f a, v2f b, v2f c) {
    return __builtin_elementwise_fma(a, b, c);   // -> v_pk_fma_f32 (gfx90a+)
}

__device__ __forceinline__ float rcpf(float x) { return __builtin_amdgcn_rcpf(x); }

// packed-pair tanh: pk algebra + 2 scalar exp/rcp. Identical per-element op
// order to the scalar version (mul, exp, add, rcp, 2t, fma, sign) -> bit-identical.
// r = 1 - 2t/(1+t) >= 0 always, so copysign degenerates to sign-OR.
__device__ __forceinline__ v2f fast_tanh2(v2f x) {
    const v2f a = __builtin_elementwise_abs(x);
    const float t0 = __expf(-2.0f * a[0]);
    const float t1 = __expf(-2.0f * a[1]);
    const v2f t  = (v2f){t0, t1};
    const v2f m  = v2s(2.0f) * t;
    const v2f rc = (v2f){rcpf(1.0f + t[0]), rcpf(1.0f + t[1])};
    const v2f r  = vfma(-m, rc, v2s(1.0f));
    const v2i ri = __builtin_bit_cast(v2i, r);
    const v2i xi = __builtin_bit_cast(v2i, x);
    const v2i res = ri | (xi & (v2i){(int)0x80000000, (int)0x80000000});
    return __builtin_bit_cast(v2f, res);
}

// lgkm-only barrier (R12-proven): orders LDS traffic without draining vmcnt.
__device__ __forceinline__ void lgkm_barrier() {
    __builtin_amdgcn_sched_barrier(0);
    asm volatile("s_waitcnt lgkmcnt(0)\n\ts_barrier" ::: "memory");
    __builtin_amdgcn_sched_barrier(0);
}

// ---- cross-lane reductions on the VALU pipe (DPP + permlane)
template<int CTRL>
__device__ __forceinline__ float dpp_addf(float v) {
    const int s = __builtin_amdgcn_update_dpp(0, __float_as_int(v), CTRL, 0xF, 0xF, true);
    return v + __int_as_float(s);
}
template<int Q>
__device__ __forceinline__ float dpp_bcast4(float v) {   // broadcast quad position Q
    const int s = __builtin_amdgcn_update_dpp(0, __float_as_int(v), Q * 0x55, 0xF, 0xF, true);
    return __int_as_float(s);
}
template<int Q>
__device__ __forceinline__ int dpp_bcast4i(int v) {      // int variant
    return __builtin_amdgcn_update_dpp(0, v, Q * 0x55, 0xF, 0xF, true);
}
__device__ __forceinline__ float pl16_sum(float v) {     // v + v[lane^16]
#if __has_builtin(__builtin_amdgcn_permlane16_swap)
    const unsigned u = __float_as_uint(v);
    const auto r = __builtin_amdgcn_permlane16_swap(u, u, false, false);
    return __uint_as_float(r[0]) + __uint_as_float(r[1]);
#else
    return v + __shfl_xor(v, 16);
#endif
}
__device__ __forceinline__ float pl32_sum(float v) {     // v + v[lane^32]
#if __has_builtin(__builtin_amdgcn_permlane32_swap)
    const unsigned u = __float_as_uint(v);
    const auto r = __builtin_amdgcn_permlane32_swap(u, u, false, false);
    return __uint_as_float(r[0]) + __uint_as_float(r[1]);
#else
    return v + __shfl_xor(v, 32);
#endif
}
// sum over the 8 kq groups (lane bits 3,4,5)
__device__ __forceinline__ float redkq8(float v) {
    v = dpp_addf<0x128>(v);      // row_ror:8 == xor8 within 16-row
    v = pl16_sum(v);
    v = pl32_sum(v);
    return v;
}
// sum over lane bits 0,1,2 (the 8 pair slots)
__device__ __forceinline__ float redpair(float v) {
    v = dpp_addf<0xB1>(v);       // quad_perm(1,0,3,2) = xor1
    v = dpp_addf<0x4E>(v);       // quad_perm(2,3,0,1) = xor2
    v = dpp_addf<0x141>(v);      // row_half_mirror   = xor7
    return v;
}
__device__ __forceinline__ float sel8f(int kq, float w0, float w1, float w2, float w3,
                                       float w4, float w5, float w6, float w7) {
    const float a = (kq & 1) ? w1 : w0;
    const float b = (kq & 1) ? w3 : w2;
    const float c = (kq & 1) ? w5 : w4;
    const float d = (kq & 1) ? w7 : w6;
    const float e = (kq & 2) ? b : a;
    const float f = (kq & 2) ? d : c;
    return (kq & 4) ? f : e;
}
}

// R18 (resubmit; container failure last round): R17 base (1835us rocprof)
// + per-quad-slot pointer state + packed tanh.
//  - lane quad-slot bq keeps ONLY bot bq's pointer/jump state (ptr_own, jt_own,
//    jb_own). The zz DPP tree already leaves bot (l&3)'s total in each lane ->
//    own-bot jump update only (was 4 bcasts + 4 np chains). baseA/ws/w8 are
//    still quad-broadcast (gathers/scatters need all 4 bots).
//  - fast_tanh2: pk algebra, 2 scalar exp/rcp, sign-OR. Bit-identical.
__global__ __launch_bounds__(512, 1)
void swarm_ring_kernel(const float* __restrict__ x,            // (B,T,8)
                       const float* __restrict__ W_in,         // (8,E)
                       const float* __restrict__ b_in,         // (E)
                       const float* __restrict__ W_out,        // (E,8)
                       const float* __restrict__ b_out,        // (8)
                       const float* __restrict__ W_p,          // (E,E)
                       const float* __restrict__ b_p,          // (E)
                       const float* __restrict__ ptr_dest,     // (NB,P)
                       const float* __restrict__ jump_W,       // (NB,E)
                       const float* __restrict__ jump_b,       // (NB)
                       const float* __restrict__ ctx_strength, // (NB)
                       const float* __restrict__ phase_bias,   // (NB,E)
                       const float* __restrict__ pointer_init, // (NB,B)
                       float* __restrict__ out)                // (B,T,8)
{
    __shared__ alignas(16) float  ring[P_ * RS_];   // 132 KiB, padded rows
    __shared__ alignas(16) float4 s4[136];          // fast: s1 4-bot packs, stride 17/16
    __shared__ alignas(16) float  sbuf[2][160];     // slow: s broadcast, pad 4f/16f
    __shared__ alignas(16) float  red[32];          // per-wave jump partials
    __shared__ alignas(16) float  hist[16][132];    // ssum history ring
    __shared__ alignas(16) float  wout_s[8][132];   // 0.25 * W_out^T

    const int tid = threadIdx.x;
    const int b   = blockIdx.x;
    const int w   = tid >> 6;
    const int l   = tid & 63;
    const int s_  = l & 7;
    const int kq  = l >> 3;                         // 0..7
    const int e0  = ((w << 3) | s_) << 1;           // owned e-pair: e0, e0+1
    const int bq  = l & 3;                          // quad slot -> owned bot index

    for (int k4 = tid; k4 < P_ * RS_ / 4; k4 += THREADS_)
        ((float4*)ring)[k4] = make_float4(0.f, 0.f, 0.f, 0.f);
    for (int idx = tid; idx < 8 * E_; idx += THREADS_) {
        const int m = idx >> 7, ee = idx & 127;
        wout_s[m][ee] = W_out[ee * 8 + m] * 0.25f;
    }

    v2f wp2[16];                                    // W_p[16*kq+kk][e0..e0+1]
    #pragma unroll
    for (int kk = 0; kk < 16; ++kk)
        wp2[kk] = *(const v2f*)(W_p + (kq * 16 + kk) * E_ + e0);

    v2f wi2[8];                                     // W_in[k][e0..e0+1]
    #pragma unroll
    for (int k = 0; k < 8; ++k)
        wi2[k] = *(const v2f*)(W_in + k * E_ + e0);

    const v2f bin2 = *(const v2f*)(b_in + e0);
    const v2f bp2  = *(const v2f*)(b_p + e0);
    const float bout_m = b_out[tid & 7];

    v2f   pb2[NB_], jw2[NB_], hid2[NB_];
    float sigc[NB_];
    #pragma unroll
    for (int i = 0; i < NB_; ++i) {
        const v2f pb = *(const v2f*)(phase_bias + i * E_ + e0);
        pb2[i] = 0.1f * pb;
        jw2[i] = *(const v2f*)(jump_W + i * E_ + e0);
        sigc[i] = 1.0f / (1.0f + __expf(-ctx_strength[i]));
        hid2[i] = (v2f){0.f, 0.f};
    }
    // per-quad-slot pointer state (bot bq only)
    float ptr_own = pointer_init[bq * B_ + b];
    const float jb_own = jump_b[bq];

    const float* xb = x + (size_t)b * T_ * 8;
    float xt[8];
    {
        float4 a0 = ((const float4*)xb)[0], a1 = ((const float4*)xb)[1];
        xt[0]=a0.x; xt[1]=a0.y; xt[2]=a0.z; xt[3]=a0.w;
        xt[4]=a1.x; xt[5]=a1.y; xt[6]=a1.z; xt[7]=a1.w;
    }

    const float Cw1 = 0.8824969f, Cw2 = 0.60653066f, Cw3 = 0.32465247f, Cw4 = 0.13533528f;
    const float Dw1 = 0.7788008f, Dw2 = 0.36787944f, Dw3 = 0.105399225f, Dw4 = 0.018315639f;

    __syncthreads();

    for (int t = 0; t < T_; ++t) {
        // ---- quad-parallel geometry: lane's quad slot bq computes bot bq
        const float p_own    = ptr_own;
        const int   base_own = (int)p_own;
        const float jt_own   = ptr_dest[(bq << 8) + base_own];
        const float f_own    = p_own - (float)base_own;
        float wsel_own, w8_own, psinv_own;
        {
            const float r  = __expf(0.25f * f_own);
            const float r2 = r * r, r3 = r2 * r, r4 = r2 * r2;
            const float ri = rcpf(r), ri2 = ri * ri, ri3 = ri2 * ri, ri4 = ri2 * ri2;
            const float p0 = Cw4*ri4, p1 = Cw3*ri3, p2 = Cw2*ri2, p3 = Cw1*ri, p4c = 1.0f,
                        p5 = Cw1*r,  p6 = Cw2*r2,  p7 = Cw3*r3,  p8 = Cw4*r4;
            const float sum = ((p0+p1)+(p2+p3)) + ((p4c+p5)+(p6+p7)) + p8;
            const float inv = rcpf(sum);
            psinv_own = inv;
            wsel_own = sel8f(kq, p0, p1, p2, p3, p4c, p5, p6, p7) * inv;
            w8_own   = p8 * inv;
        }
        // broadcast bot-q values needed by ALL lanes (quad_perm, VALU)
        int   baseA[NB_];
        float ws[NB_], w8[NB_];
        baseA[0] = dpp_bcast4i<0>(base_own); baseA[1] = dpp_bcast4i<1>(base_own);
        baseA[2] = dpp_bcast4i<2>(base_own); baseA[3] = dpp_bcast4i<3>(base_own);
        ws[0] = dpp_bcast4<0>(wsel_own); ws[1] = dpp_bcast4<1>(wsel_own);
        ws[2] = dpp_bcast4<2>(wsel_own); ws[3] = dpp_bcast4<3>(wsel_own);
        w8[0] = dpp_bcast4<0>(w8_own); w8[1] = dpp_bcast4<1>(w8_own);
        w8[2] = dpp_bcast4<2>(w8_own); w8[3] = dpp_bcast4<3>(w8_own);

        // ---- block-uniform independence test
        int ddm[NB_][NB_];
        bool overlap = false;
        #pragma unroll
        for (int j = 1; j < NB_; ++j)
            #pragma unroll
            for (int i = 0; i < j; ++i) {
                const int dd = ((baseA[j] - baseA[i] + 128) & 255) - 128;
                ddm[j][i] = dd;
                overlap = overlap || (dd >= -8 && dd <= 8);
            }

        // ---- gathers: row kq-4 per group (+row +4 on kq0), b64 packed math
        v2f ctxp2[NB_];
        #pragma unroll
        for (int i = 0; i < NB_; ++i) {
            const int r0 = (baseA[i] + kq - K_) & (P_ - 1);
            const v2f g0 = *(const v2f*)(ring + r0 * RS_ + e0);
            v2f c = v2s(ws[i]) * g0;
            if (kq == 0) {
                const int r2 = (baseA[i] + K_) & (P_ - 1);
                const v2f g2 = *(const v2f*)(ring + r2 * RS_ + e0);
                c = vfma(v2s(w8[i]), g2, c);
            }
            ctxp2[i] = (v2f){redkq8(c[0]), redkq8(c[1])};
        }

        // ---- inp = x_t @ W_in + b_in (packed)
        v2f inp2 = bin2;
        #pragma unroll
        for (int k = 0; k < 8; ++k)
            inp2 = vfma(v2s(xt[k]), wi2[k], inp2);

        float xtn[8];
        if (t + 1 < T_) {
            float4 a0 = ((const float4*)(xb + (t + 1) * 8))[0];
            float4 a1 = ((const float4*)(xb + (t + 1) * 8))[1];
            xtn[0]=a0.x; xtn[1]=a0.y; xtn[2]=a0.z; xtn[3]=a0.w;
            xtn[4]=a1.x; xtn[5]=a1.y; xtn[6]=a1.z; xtn[7]=a1.w;
        } else {
            #pragma unroll
            for (int k = 0; k < 8; ++k) xtn[k] = 0.f;
        }

        v2f sv2[NB_];

        if (!overlap) {
            // ================= FAST PATH: all 4 bots independent =================
            v2f s1v[NB_];
            #pragma unroll
            for (int j = 0; j < NB_; ++j) {
                const v2f pre = (inp2 + pb2[j]) + hid2[j];
                s1v[j] = fast_tanh2(vfma(v2s(sigc[j]), ctxp2[j], pre));
            }
            if (kq == 0) {
                const int si = 17 * w + (s_ << 1);   // e0 + (e0>>4)
                s4[si]     = make_float4(s1v[0][0], s1v[1][0], s1v[2][0], s1v[3][0]);
                s4[si + 1] = make_float4(s1v[0][1], s1v[1][1], s1v[2][1], s1v[3][1]);
            }
            lgkm_barrier();                         // ONE barrier for all 4 broadcasts

            v2f ab0 = (v2f){0.f, 0.f}, ab1 = ab0, ab2 = ab0, ab3 = ab0;
            const float4* sp = s4 + kq * 17;        // padded: idx(16kq+kk)=17kq+kk
            #pragma unroll
            for (int kk = 0; kk < 16; ++kk) {
                const float4 sq = sp[kk];
                const v2f w2 = wp2[kk];
                ab0 = vfma(v2s(sq.x), w2, ab0);
                ab1 = vfma(v2s(sq.y), w2, ab1);
                ab2 = vfma(v2s(sq.z), w2, ab2);
                ab3 = vfma(v2s(sq.w), w2, ab3);
            }
            sv2[0] = fast_tanh2((v2f){redkq8(ab0[0]), redkq8(ab0[1])} + bp2);
            sv2[1] = fast_tanh2((v2f){redkq8(ab1[0]), redkq8(ab1[1])} + bp2);
            sv2[2] = fast_tanh2((v2f){redkq8(ab2[0]), redkq8(ab2[1])} + bp2);
            sv2[3] = fast_tanh2((v2f){redkq8(ab3[0]), redkq8(ab3[1])} + bp2);
            #pragma unroll
            for (int j = 0; j < NB_; ++j) hid2[j] = sv2[j];

            // disjoint b64 scatters: lane owns row kq-4 (+row +4 on kq0)
            #pragma unroll
            for (int j = 0; j < NB_; ++j) {
                const v2f s = sv2[j];
                const int r0 = (baseA[j] + kq - K_) & (P_ - 1);
                v2f* q0 = (v2f*)(ring + r0 * RS_ + e0);
                *q0 = vfma(v2s(ws[j]), s, *q0);
                if (kq == 0) {
                    const int r2 = (baseA[j] + K_) & (P_ - 1);
                    v2f* q2 = (v2f*)(ring + r2 * RS_ + e0);
                    *q2 = vfma(v2s(w8[j]), s, *q2);
                }
            }
        } else {
            // ================= SLOW PATH: serial chain with coef corrections =====
            float fA[NB_], psinv[NB_];
            fA[0] = dpp_bcast4<0>(f_own); fA[1] = dpp_bcast4<1>(f_own);
            fA[2] = dpp_bcast4<2>(f_own); fA[3] = dpp_bcast4<3>(f_own);
            psinv[0] = dpp_bcast4<0>(psinv_own); psinv[1] = dpp_bcast4<1>(psinv_own);
            psinv[2] = dpp_bcast4<2>(psinv_own); psinv[3] = dpp_bcast4<3>(psinv_own);

            float coefm[NB_][NB_];
            #pragma unroll
            for (int j = 1; j < NB_; ++j) {
                #pragma unroll
                for (int i = 0; i < j; ++i) {
                    const int dd = ddm[j][i];
                    float c = 0.f;
                    if (dd >= -8 && dd <= 8) {
                        const float A = (float)dd - fA[i];
                        const float s  = __expf(-0.25f * (A - fA[j]));
                        const float G  = __expf(0.125f * (fA[i] * fA[i] - A * A));
                        const float s2p = s * s, s3p = s2p * s, s4p = s2p * s2p;
                        const float si = rcpf(s), si2 = si * si, si3 = si2 * si, si4 = si2 * si2;
                        float acc = 0.f;
                        acc += (dd >= 0)              ? Dw4 * si4 : 0.f;
                        acc += (dd >= -1 && dd <= 7)  ? Dw3 * si3 : 0.f;
                        acc += (dd >= -2 && dd <= 6)  ? Dw2 * si2 : 0.f;
                        acc += (dd >= -3 && dd <= 5)  ? Dw1 * si  : 0.f;
                        acc += (dd >= -4 && dd <= 4)  ? 1.0f      : 0.f;
                        acc += (dd >= -5 && dd <= 3)  ? Dw1 * s   : 0.f;
                        acc += (dd >= -6 && dd <= 2)  ? Dw2 * s2p : 0.f;
                        acc += (dd >= -7 && dd <= 1)  ? Dw3 * s3p : 0.f;
                        acc += (dd <= 0)              ? Dw4 * s4p : 0.f;
                        c = psinv[i] * psinv[j] * G * acc;
                    }
                    coefm[j][i] = c;
                }
            }

            #pragma unroll
            for (int j = 0; j < NB_; ++j) {
                v2f ctx = ctxp2[j];
                #pragma unroll
                for (int i = 0; i < j; ++i)
                    ctx = vfma(v2s(coefm[j][i]), sv2[i], ctx);
                const v2f pre = (inp2 + pb2[j]) + hid2[j];
                const v2f s1  = fast_tanh2(vfma(v2s(sigc[j]), ctx, pre));
                if (kq == 0) {
                    const int pf = 20 * w + (s_ << 1);   // e0 + 4*(e0>>4)
                    *(v2f*)(&sbuf[j & 1][pf]) = s1;
                }
                lgkm_barrier();                     // s broadcast ready

                const float4* sp4 = (const float4*)(&sbuf[j & 1][0]);
                v2f axy = (v2f){0.f, 0.f};
                #pragma unroll
                for (int m = 0; m < 4; ++m) {
                    const float4 sq = sp4[5 * kq + m];   // padded: fidx(4kq+m)=5kq+m
                    axy = vfma(v2s(sq.x), wp2[4*m+0], axy);
                    axy = vfma(v2s(sq.y), wp2[4*m+1], axy);
                    axy = vfma(v2s(sq.z), wp2[4*m+2], axy);
                    axy = vfma(v2s(sq.w), wp2[4*m+3], axy);
                }
                const v2f s2 = fast_tanh2((v2f){redkq8(axy[0]), redkq8(axy[1])} + bp2);
                sv2[j] = s2; hid2[j] = s2;

                const int r0 = (baseA[j] + kq - K_) & (P_ - 1);
                v2f* q0 = (v2f*)(ring + r0 * RS_ + e0);
                *q0 = vfma(v2s(ws[j]), s2, *q0);
                if (kq == 0) {
                    const int r2 = (baseA[j] + K_) & (P_ - 1);
                    v2f* q2 = (v2f*)(ring + r2 * RS_ + e0);
                    *q2 = vfma(v2s(w8[j]), s2, *q2);
                }
            }
        }

        // ---- jump dots: per-lane pair dot, reduce the 8 pair slots on VALU
        {
            float vj0 = fmaf(sv2[0][1], jw2[0][1], sv2[0][0] * jw2[0][0]);
            float vj1 = fmaf(sv2[1][1], jw2[1][1], sv2[1][0] * jw2[1][0]);
            float vj2 = fmaf(sv2[2][1], jw2[2][1], sv2[2][0] * jw2[2][0]);
            float vj3 = fmaf(sv2[3][1], jw2[3][1], sv2[3][0] * jw2[3][0]);
            vj0 = redpair(vj0); vj1 = redpair(vj1); vj2 = redpair(vj2); vj3 = redpair(vj3);
            if (l == 0)
                ((float4*)red)[w] = make_float4(vj0, vj1, vj2, vj3);
        }

        // ---- ssum -> history ring (kq0 lanes, b64, packed adds)
        {
            const v2f ssum2 = (sv2[0] + sv2[1]) + (sv2[2] + sv2[3]);
            if (kq == 0) *(v2f*)(&hist[t & 15][e0]) = ssum2;
        }

        lgkm_barrier();                             // scatters + red + hist visible

        // ---- zz combine: 1 b32 read + DPP tree; lane ends holding bot (l&3)'s
        // total -> own-bot jump update only
        {
            float rv = red[l & 31];
            rv = dpp_addf<0x124>(rv);               // row_ror:4 -> + same-bot, w'+1
            rv = dpp_addf<0x128>(rv);               // row_ror:8 -> all w' in 16-row
            rv = pl16_sum(rv);                      // + other 16-row
            const float zz = rv + jb_own;
            float np;
            if (zz > 0.0f) np = jt_own;
            else { np = ptr_own + 1.0f; if (np >= 256.0f) np -= 256.0f; }
            ptr_own = np;
        }

        // ---- every 8th step: out dots spread over all 8 waves
        if ((t & 7) == 7) {
            const int tt = w;
            const int m  = l >> 3;
            const int c4 = l & 7;
            const float* hrow = hist[(t - 7 + tt) & 15];
            const float* wrow = wout_s[m];
            float acc = 0.f;
            #pragma unroll
            for (int q = 0; q < 4; ++q) {
                const float4 h4 = ((const float4*)hrow)[c4 * 4 + q];
                const float4 w4 = ((const float4*)wrow)[c4 * 4 + q];
                acc += ((h4.x * w4.x + h4.y * w4.y) + (h4.z * w4.z + h4.w * w4.w));
            }
            acc = redpair(acc);
            if ((l & 7) == 0)
                out[((size_t)b * T_ + (t - 7 + tt)) * 8 + m] = acc + bout_m;
        }

        #pragma unroll
        for (int k = 0; k < 8; ++k) xt[k] = xtn[k];
    }
}

extern "C" void kernel_launch(void* const* d_in, const int* in_sizes, int n_in,
                              void* d_out, int out_size, void* d_ws, size_t ws_size,
                              hipStream_t stream) {
    (void)in_sizes; (void)n_in; (void)out_size; (void)d_ws; (void)ws_size;
    swarm_ring_kernel<<<dim3(B_), dim3(512), 0, stream>>>(
        (const float*)d_in[0],  (const float*)d_in[1],  (const float*)d_in[2],
        (const float*)d_in[3],  (const float*)d_in[4],  (const float*)d_in[5],
        (const float*)d_in[6],  (const float*)d_in[7],  (const float*)d_in[8],
        (const float*)d_in[9],  (const float*)d_in[10], (const float*)d_in[11],
        (const float*)d_in[12], (float*)d_out);
}

// Round 12
// 1891.660 us; speedup vs baseline: 1.0326x; 1.0326x over previous
//
#include <hip/hip_runtime.h>
#include <cmath>

namespace {
constexpr int B_ = 16, T_ = 512, P_ = 256, E_ = 128, NB_ = 4, K_ = 4;
constexpr int THREADS_ = 512;
constexpr int RS_ = 132;   // padded ring row stride (floats): rows shift banks by 4

typedef float v2f __attribute__((ext_vector_type(2)));
__device__ __forceinline__ v2f v2s(float s) { return (v2f){s, s}; }
__device__ __forceinline__ v2f vfma(v2f a, v2f b, v2f c) {
    return __builtin_elementwise_fma(a, b, c);   // -> v_pk_fma_f32 (gfx90a+)
}

__device__ __forceinline__ float rcpf(float x) { return __builtin_amdgcn_rcpf(x); }
__device__ __forceinline__ float fast_tanh(float x) {
    float a = fabsf(x);
    float t = __expf(-2.0f * a);
    float r = 1.0f - 2.0f * t * rcpf(1.0f + t);
    return copysignf(r, x);
}

// lgkm-only barrier (R12-proven): orders LDS traffic without draining vmcnt.
__device__ __forceinline__ void lgkm_barrier() {
    __builtin_amdgcn_sched_barrier(0);
    asm volatile("s_waitcnt lgkmcnt(0)\n\ts_barrier" ::: "memory");
    __builtin_amdgcn_sched_barrier(0);
}

// ---- cross-lane reductions on the VALU pipe (DPP + permlane)
template<int CTRL>
__device__ __forceinline__ float dpp_addf(float v) {
    const int s = __builtin_amdgcn_update_dpp(0, __float_as_int(v), CTRL, 0xF, 0xF, true);
    return v + __int_as_float(s);
}
template<int Q>
__device__ __forceinline__ float dpp_bcast4(float v) {   // broadcast quad position Q
    const int s = __builtin_amdgcn_update_dpp(0, __float_as_int(v), Q * 0x55, 0xF, 0xF, true);
    return __int_as_float(s);
}
template<int Q>
__device__ __forceinline__ int dpp_bcast4i(int v) {      // int variant
    return __builtin_amdgcn_update_dpp(0, v, Q * 0x55, 0xF, 0xF, true);
}
__device__ __forceinline__ float pl16_sum(float v) {     // v + v[lane^16]
#if __has_builtin(__builtin_amdgcn_permlane16_swap)
    const unsigned u = __float_as_uint(v);
    const auto r = __builtin_amdgcn_permlane16_swap(u, u, false, false);
    return __uint_as_float(r[0]) + __uint_as_float(r[1]);
#else
    return v + __shfl_xor(v, 16);
#endif
}
__device__ __forceinline__ float pl32_sum(float v) {     // v + v[lane^32]
#if __has_builtin(__builtin_amdgcn_permlane32_swap)
    const unsigned u = __float_as_uint(v);
    const auto r = __builtin_amdgcn_permlane32_swap(u, u, false, false);
    return __uint_as_float(r[0]) + __uint_as_float(r[1]);
#else
    return v + __shfl_xor(v, 32);
#endif
}
// sum over the 8 kq groups (lane bits 3,4,5)
__device__ __forceinline__ float redkq8(float v) {
    v = dpp_addf<0x128>(v);      // row_ror:8 == xor8 within 16-row
    v = pl16_sum(v);
    v = pl32_sum(v);
    return v;
}
// sum over lane bits 0,1,2 (the 8 pair slots)
__device__ __forceinline__ float redpair(float v) {
    v = dpp_addf<0xB1>(v);       // quad_perm(1,0,3,2) = xor1
    v = dpp_addf<0x4E>(v);       // quad_perm(2,3,0,1) = xor2
    v = dpp_addf<0x141>(v);      // row_half_mirror   = xor7
    return v;
}
__device__ __forceinline__ float sel8f(int kq, float w0, float w1, float w2, float w3,
                                       float w4, float w5, float w6, float w7) {
    const float a = (kq & 1) ? w1 : w0;
    const float b = (kq & 1) ? w3 : w2;
    const float c = (kq & 1) ? w5 : w4;
    const float d = (kq & 1) ? w7 : w6;
    const float e = (kq & 2) ? b : a;
    const float f = (kq & 2) ? d : c;
    return (kq & 4) ? f : e;
}
}

// R19 = R17 exact revert (best verified: 1835us rocprof / 1902us bench).
// R18's per-quad pointer-state + packed-tanh measured +65us with identical
// absolute VALU cycles and identical bank conflicts -> either session noise
// or a genuine scheduling regression; both metrics favor R17, so R17 is the
// final configuration. Structure: 512thr/8 waves, e-PAIR 8-way k-split,
// quad-parallel geometry (R16), packed v_pk_fma_f32 math + spread out-dots
// (R17), lgkm-only barriers (R12), padded ring rows (R11b).
__global__ __launch_bounds__(512, 1)
void swarm_ring_kernel(const float* __restrict__ x,            // (B,T,8)
                       const float* __restrict__ W_in,         // (8,E)
                       const float* __restrict__ b_in,         // (E)
                       const float* __restrict__ W_out,        // (E,8)
                       const float* __restrict__ b_out,        // (8)
                       const float* __restrict__ W_p,          // (E,E)
                       const float* __restrict__ b_p,          // (E)
                       const float* __restrict__ ptr_dest,     // (NB,P)
                       const float* __restrict__ jump_W,       // (NB,E)
                       const float* __restrict__ jump_b,       // (NB)
                       const float* __restrict__ ctx_strength, // (NB)
                       const float* __restrict__ phase_bias,   // (NB,E)
                       const float* __restrict__ pointer_init, // (NB,B)
                       float* __restrict__ out)                // (B,T,8)
{
    __shared__ alignas(16) float  ring[P_ * RS_];   // 132 KiB, padded rows
    __shared__ alignas(16) float4 s4[136];          // fast: s1 4-bot packs, stride 17/16
    __shared__ alignas(16) float  sbuf[2][160];     // slow: s broadcast, pad 4f/16f
    __shared__ alignas(16) float  red[32];          // per-wave jump partials
    __shared__ alignas(16) float  hist[16][132];    // ssum history ring
    __shared__ alignas(16) float  wout_s[8][132];   // 0.25 * W_out^T

    const int tid = threadIdx.x;
    const int b   = blockIdx.x;
    const int w   = tid >> 6;
    const int l   = tid & 63;
    const int s_  = l & 7;
    const int kq  = l >> 3;                         // 0..7
    const int e0  = ((w << 3) | s_) << 1;           // owned e-pair: e0, e0+1
    const int bq  = l & 3;                          // quad slot -> bot index

    for (int k4 = tid; k4 < P_ * RS_ / 4; k4 += THREADS_)
        ((float4*)ring)[k4] = make_float4(0.f, 0.f, 0.f, 0.f);
    for (int idx = tid; idx < 8 * E_; idx += THREADS_) {
        const int m = idx >> 7, ee = idx & 127;
        wout_s[m][ee] = W_out[ee * 8 + m] * 0.25f;
    }

    v2f wp2[16];                                    // W_p[16*kq+kk][e0..e0+1]
    #pragma unroll
    for (int kk = 0; kk < 16; ++kk)
        wp2[kk] = *(const v2f*)(W_p + (kq * 16 + kk) * E_ + e0);

    v2f wi2[8];                                     // W_in[k][e0..e0+1]
    #pragma unroll
    for (int k = 0; k < 8; ++k)
        wi2[k] = *(const v2f*)(W_in + k * E_ + e0);

    const v2f bin2 = *(const v2f*)(b_in + e0);
    const v2f bp2  = *(const v2f*)(b_p + e0);
    const float bout_m = b_out[tid & 7];

    v2f   pb2[NB_], jw2[NB_], hid2[NB_];
    float sigc[NB_], jb_r[NB_], ptrv[NB_];
    #pragma unroll
    for (int i = 0; i < NB_; ++i) {
        const v2f pb = *(const v2f*)(phase_bias + i * E_ + e0);
        pb2[i] = 0.1f * pb;
        jw2[i] = *(const v2f*)(jump_W + i * E_ + e0);
        sigc[i] = 1.0f / (1.0f + __expf(-ctx_strength[i]));
        jb_r[i] = jump_b[i];
        hid2[i] = (v2f){0.f, 0.f};
        ptrv[i] = pointer_init[i * B_ + b];
    }

    const float* xb = x + (size_t)b * T_ * 8;
    float xt[8];
    {
        float4 a0 = ((const float4*)xb)[0], a1 = ((const float4*)xb)[1];
        xt[0]=a0.x; xt[1]=a0.y; xt[2]=a0.z; xt[3]=a0.w;
        xt[4]=a1.x; xt[5]=a1.y; xt[6]=a1.z; xt[7]=a1.w;
    }

    const float Cw1 = 0.8824969f, Cw2 = 0.60653066f, Cw3 = 0.32465247f, Cw4 = 0.13533528f;
    const float Dw1 = 0.7788008f, Dw2 = 0.36787944f, Dw3 = 0.105399225f, Dw4 = 0.018315639f;

    __syncthreads();

    for (int t = 0; t < T_; ++t) {
        // ---- quad-parallel geometry: lane's quad slot bq computes bot bq
        const float p_own    = ptrv[0] * 0.f + ((bq == 0) ? ptrv[0] : (bq == 1) ? ptrv[1] : (bq == 2) ? ptrv[2] : ptrv[3]);
        const int   base_own = (int)p_own;
        const float jt_own   = ptr_dest[(bq << 8) + base_own];
        const float f_own    = p_own - (float)base_own;
        float wsel_own, w8_own, psinv_own;
        {
            const float r  = __expf(0.25f * f_own);
            const float r2 = r * r, r3 = r2 * r, r4 = r2 * r2;
            const float ri = rcpf(r), ri2 = ri * ri, ri3 = ri2 * ri, ri4 = ri2 * ri2;
            const float p0 = Cw4*ri4, p1 = Cw3*ri3, p2 = Cw2*ri2, p3 = Cw1*ri, p4c = 1.0f,
                        p5 = Cw1*r,  p6 = Cw2*r2,  p7 = Cw3*r3,  p8 = Cw4*r4;
            const float sum = ((p0+p1)+(p2+p3)) + ((p4c+p5)+(p6+p7)) + p8;
            const float inv = rcpf(sum);
            psinv_own = inv;
            wsel_own = sel8f(kq, p0, p1, p2, p3, p4c, p5, p6, p7) * inv;
            w8_own   = p8 * inv;
        }
        // broadcast bot-q values to all lanes (quad_perm, VALU)
        int   baseA[NB_];
        float jt[NB_], ws[NB_], w8[NB_];
        baseA[0] = dpp_bcast4i<0>(base_own); baseA[1] = dpp_bcast4i<1>(base_own);
        baseA[2] = dpp_bcast4i<2>(base_own); baseA[3] = dpp_bcast4i<3>(base_own);
        jt[0] = dpp_bcast4<0>(jt_own); jt[1] = dpp_bcast4<1>(jt_own);
        jt[2] = dpp_bcast4<2>(jt_own); jt[3] = dpp_bcast4<3>(jt_own);
        ws[0] = dpp_bcast4<0>(wsel_own); ws[1] = dpp_bcast4<1>(wsel_own);
        ws[2] = dpp_bcast4<2>(wsel_own); ws[3] = dpp_bcast4<3>(wsel_own);
        w8[0] = dpp_bcast4<0>(w8_own); w8[1] = dpp_bcast4<1>(w8_own);
        w8[2] = dpp_bcast4<2>(w8_own); w8[3] = dpp_bcast4<3>(w8_own);

        // ---- block-uniform independence test
        int ddm[NB_][NB_];
        bool overlap = false;
        #pragma unroll
        for (int j = 1; j < NB_; ++j)
            #pragma unroll
            for (int i = 0; i < j; ++i) {
                const int dd = ((baseA[j] - baseA[i] + 128) & 255) - 128;
                ddm[j][i] = dd;
                overlap = overlap || (dd >= -8 && dd <= 8);
            }

        // ---- gathers: row kq-4 per group (+row +4 on kq0), b64 packed math
        v2f ctxp2[NB_];
        #pragma unroll
        for (int i = 0; i < NB_; ++i) {
            const int r0 = (baseA[i] + kq - K_) & (P_ - 1);
            const v2f g0 = *(const v2f*)(ring + r0 * RS_ + e0);
            v2f c = v2s(ws[i]) * g0;
            if (kq == 0) {
                const int r2 = (baseA[i] + K_) & (P_ - 1);
                const v2f g2 = *(const v2f*)(ring + r2 * RS_ + e0);
                c = vfma(v2s(w8[i]), g2, c);
            }
            ctxp2[i] = (v2f){redkq8(c[0]), redkq8(c[1])};
        }

        // ---- inp = x_t @ W_in + b_in (packed)
        v2f inp2 = bin2;
        #pragma unroll
        for (int k = 0; k < 8; ++k)
            inp2 = vfma(v2s(xt[k]), wi2[k], inp2);

        float xtn[8];
        if (t + 1 < T_) {
            float4 a0 = ((const float4*)(xb + (t + 1) * 8))[0];
            float4 a1 = ((const float4*)(xb + (t + 1) * 8))[1];
            xtn[0]=a0.x; xtn[1]=a0.y; xtn[2]=a0.z; xtn[3]=a0.w;
            xtn[4]=a1.x; xtn[5]=a1.y; xtn[6]=a1.z; xtn[7]=a1.w;
        } else {
            #pragma unroll
            for (int k = 0; k < 8; ++k) xtn[k] = 0.f;
        }

        v2f sv2[NB_];

        if (!overlap) {
            // ================= FAST PATH: all 4 bots independent =================
            v2f s1v[NB_];
            #pragma unroll
            for (int j = 0; j < NB_; ++j) {
                const v2f pre = (inp2 + pb2[j]) + hid2[j];
                const v2f z   = vfma(v2s(sigc[j]), ctxp2[j], pre);
                s1v[j] = (v2f){fast_tanh(z[0]), fast_tanh(z[1])};
            }
            if (kq == 0) {
                const int si = 17 * w + (s_ << 1);   // e0 + (e0>>4)
                s4[si]     = make_float4(s1v[0][0], s1v[1][0], s1v[2][0], s1v[3][0]);
                s4[si + 1] = make_float4(s1v[0][1], s1v[1][1], s1v[2][1], s1v[3][1]);
            }
            lgkm_barrier();                         // ONE barrier for all 4 broadcasts

            v2f ab0 = (v2f){0.f, 0.f}, ab1 = ab0, ab2 = ab0, ab3 = ab0;
            const float4* sp = s4 + kq * 17;        // padded: idx(16kq+kk)=17kq+kk
            #pragma unroll
            for (int kk = 0; kk < 16; ++kk) {
                const float4 sq = sp[kk];
                const v2f w2 = wp2[kk];
                ab0 = vfma(v2s(sq.x), w2, ab0);
                ab1 = vfma(v2s(sq.y), w2, ab1);
                ab2 = vfma(v2s(sq.z), w2, ab2);
                ab3 = vfma(v2s(sq.w), w2, ab3);
            }
            sv2[0] = (v2f){fast_tanh(redkq8(ab0[0]) + bp2[0]), fast_tanh(redkq8(ab0[1]) + bp2[1])};
            sv2[1] = (v2f){fast_tanh(redkq8(ab1[0]) + bp2[0]), fast_tanh(redkq8(ab1[1]) + bp2[1])};
            sv2[2] = (v2f){fast_tanh(redkq8(ab2[0]) + bp2[0]), fast_tanh(redkq8(ab2[1]) + bp2[1])};
            sv2[3] = (v2f){fast_tanh(redkq8(ab3[0]) + bp2[0]), fast_tanh(redkq8(ab3[1]) + bp2[1])};
            #pragma unroll
            for (int j = 0; j < NB_; ++j) hid2[j] = sv2[j];

            // disjoint b64 scatters: lane owns row kq-4 (+row +4 on kq0)
            #pragma unroll
            for (int j = 0; j < NB_; ++j) {
                const v2f s = sv2[j];
                const int r0 = (baseA[j] + kq - K_) & (P_ - 1);
                v2f* q0 = (v2f*)(ring + r0 * RS_ + e0);
                *q0 = vfma(v2s(ws[j]), s, *q0);
                if (kq == 0) {
                    const int r2 = (baseA[j] + K_) & (P_ - 1);
                    v2f* q2 = (v2f*)(ring + r2 * RS_ + e0);
                    *q2 = vfma(v2s(w8[j]), s, *q2);
                }
            }
        } else {
            // ================= SLOW PATH: serial chain with coef corrections =====
            float fA[NB_], psinv[NB_];
            fA[0] = dpp_bcast4<0>(f_own); fA[1] = dpp_bcast4<1>(f_own);
            fA[2] = dpp_bcast4<2>(f_own); fA[3] = dpp_bcast4<3>(f_own);
            psinv[0] = dpp_bcast4<0>(psinv_own); psinv[1] = dpp_bcast4<1>(psinv_own);
            psinv[2] = dpp_bcast4<2>(psinv_own); psinv[3] = dpp_bcast4<3>(psinv_own);

            float coefm[NB_][NB_];
            #pragma unroll
            for (int j = 1; j < NB_; ++j) {
                #pragma unroll
                for (int i = 0; i < j; ++i) {
                    const int dd = ddm[j][i];
                    float c = 0.f;
                    if (dd >= -8 && dd <= 8) {
                        const float A = (float)dd - fA[i];
                        const float s  = __expf(-0.25f * (A - fA[j]));
                        const float G  = __expf(0.125f * (fA[i] * fA[i] - A * A));
                        const float s2p = s * s, s3p = s2p * s, s4p = s2p * s2p;
                        const float si = rcpf(s), si2 = si * si, si3 = si2 * si, si4 = si2 * si2;
                        float acc = 0.f;
                        acc += (dd >= 0)              ? Dw4 * si4 : 0.f;
                        acc += (dd >= -1 && dd <= 7)  ? Dw3 * si3 : 0.f;
                        acc += (dd >= -2 && dd <= 6)  ? Dw2 * si2 : 0.f;
                        acc += (dd >= -3 && dd <= 5)  ? Dw1 * si  : 0.f;
                        acc += (dd >= -4 && dd <= 4)  ? 1.0f      : 0.f;
                        acc += (dd >= -5 && dd <= 3)  ? Dw1 * s   : 0.f;
                        acc += (dd >= -6 && dd <= 2)  ? Dw2 * s2p : 0.f;
                        acc += (dd >= -7 && dd <= 1)  ? Dw3 * s3p : 0.f;
                        acc += (dd <= 0)              ? Dw4 * s4p : 0.f;
                        c = psinv[i] * psinv[j] * G * acc;
                    }
                    coefm[j][i] = c;
                }
            }

            #pragma unroll
            for (int j = 0; j < NB_; ++j) {
                v2f ctx = ctxp2[j];
                #pragma unroll
                for (int i = 0; i < j; ++i)
                    ctx = vfma(v2s(coefm[j][i]), sv2[i], ctx);
                const v2f pre = (inp2 + pb2[j]) + hid2[j];
                const v2f z   = vfma(v2s(sigc[j]), ctx, pre);
                const v2f s1  = (v2f){fast_tanh(z[0]), fast_tanh(z[1])};
                if (kq == 0) {
                    const int pf = 20 * w + (s_ << 1);   // e0 + 4*(e0>>4)
                    *(v2f*)(&sbuf[j & 1][pf]) = s1;
                }
                lgkm_barrier();                     // s broadcast ready

                const float4* sp4 = (const float4*)(&sbuf[j & 1][0]);
                v2f axy = (v2f){0.f, 0.f};
                #pragma unroll
                for (int m = 0; m < 4; ++m) {
                    const float4 sq = sp4[5 * kq + m];   // padded: fidx(4kq+m)=5kq+m
                    axy = vfma(v2s(sq.x), wp2[4*m+0], axy);
                    axy = vfma(v2s(sq.y), wp2[4*m+1], axy);
                    axy = vfma(v2s(sq.z), wp2[4*m+2], axy);
                    axy = vfma(v2s(sq.w), wp2[4*m+3], axy);
                }
                v2f s2;
                s2[0] = fast_tanh(redkq8(axy[0]) + bp2[0]);
                s2[1] = fast_tanh(redkq8(axy[1]) + bp2[1]);
                sv2[j] = s2; hid2[j] = s2;

                const int r0 = (baseA[j] + kq - K_) & (P_ - 1);
                v2f* q0 = (v2f*)(ring + r0 * RS_ + e0);
                *q0 = vfma(v2s(ws[j]), s2, *q0);
                if (kq == 0) {
                    const int r2 = (baseA[j] + K_) & (P_ - 1);
                    v2f* q2 = (v2f*)(ring + r2 * RS_ + e0);
                    *q2 = vfma(v2s(w8[j]), s2, *q2);
                }
            }
        }

        // ---- jump dots: per-lane pair dot, reduce the 8 pair slots on VALU
        {
            float vj0 = fmaf(sv2[0][1], jw2[0][1], sv2[0][0] * jw2[0][0]);
            float vj1 = fmaf(sv2[1][1], jw2[1][1], sv2[1][0] * jw2[1][0]);
            float vj2 = fmaf(sv2[2][1], jw2[2][1], sv2[2][0] * jw2[2][0]);
            float vj3 = fmaf(sv2[3][1], jw2[3][1], sv2[3][0] * jw2[3][0]);
            vj0 = redpair(vj0); vj1 = redpair(vj1); vj2 = redpair(vj2); vj3 = redpair(vj3);
            if (l == 0)
                ((float4*)red)[w] = make_float4(vj0, vj1, vj2, vj3);
        }

        // ---- ssum -> history ring (kq0 lanes, b64, packed adds)
        {
            const v2f ssum2 = (sv2[0] + sv2[1]) + (sv2[2] + sv2[3]);
            if (kq == 0) *(v2f*)(&hist[t & 15][e0]) = ssum2;
        }

        lgkm_barrier();                             // scatters + red + hist visible

        // ---- zz combine: 1 b32 read + DPP tree (lane l holds red[4w'+bot])
        {
            float rv = red[l & 31];
            rv = dpp_addf<0x124>(rv);               // row_ror:4 -> + same-bot, w'+1
            rv = dpp_addf<0x128>(rv);               // row_ror:8 -> all w' in 16-row
            rv = pl16_sum(rv);                      // + other 16-row
            const float zz0 = dpp_bcast4<0>(rv) + jb_r[0];
            const float zz1 = dpp_bcast4<1>(rv) + jb_r[1];
            const float zz2 = dpp_bcast4<2>(rv) + jb_r[2];
            const float zz3 = dpp_bcast4<3>(rv) + jb_r[3];
            const float zz[4] = { zz0, zz1, zz2, zz3 };
            #pragma unroll
            for (int i = 0; i < NB_; ++i) {
                float np;
                if (zz[i] > 0.0f) np = jt[i];
                else { np = ptrv[i] + 1.0f; if (np >= 256.0f) np -= 256.0f; }
                ptrv[i] = np;
            }
        }

        // ---- every 8th step: out dots spread over all 8 waves
        if ((t & 7) == 7) {
            const int tt = w;
            const int m  = l >> 3;
            const int c4 = l & 7;
            const float* hrow = hist[(t - 7 + tt) & 15];
            const float* wrow = wout_s[m];
            float acc = 0.f;
            #pragma unroll
            for (int q = 0; q < 4; ++q) {
                const float4 h4 = ((const float4*)hrow)[c4 * 4 + q];
                const float4 w4 = ((const float4*)wrow)[c4 * 4 + q];
                acc += ((h4.x * w4.x + h4.y * w4.y) + (h4.z * w4.z + h4.w * w4.w));
            }
            acc = redpair(acc);
            if ((l & 7) == 0)
                out[((size_t)b * T_ + (t - 7 + tt)) * 8 + m] = acc + bout_m;
        }

        #pragma unroll
        for (int k = 0; k < 8; ++k) xt[k] = xtn[k];
    }
}

extern "C" void kernel_launch(void* const* d_in, const int* in_sizes, int n_in,
                              void* d_out, int out_size, void* d_ws, size_t ws_size,
                              hipStream_t stream) {
    (void)in_sizes; (void)n_in; (void)out_size; (void)d_ws; (void)ws_size;
    swarm_ring_kernel<<<dim3(B_), dim3(512), 0, stream>>>(
        (const float*)d_in[0],  (const float*)d_in[1],  (const float*)d_in[2],
        (const float*)d_in[3],  (const float*)d_in[4],  (const float*)d_in[5],
        (const float*)d_in[6],  (const float*)d_in[7],  (const float*)d_in[8],
        (const float*)d_in[9],  (const float*)d_in[10], (const float*)d_in[11],
        (const float*)d_in[12], (float*)d_out);
}